// Round 4
// baseline (185.598 us; speedup 1.0000x reference)
//
#include <hip/hip_runtime.h>
#include <hip/hip_cooperative_groups.h>

namespace cg = cooperative_groups;

// Reservoir sampling "add" — single cooperative kernel, 3 phases:
//   A: winner[s] = fill-phase winner (plain stores, covers all n slots)
//   grid.sync
//   B: random-phase samples (idx >= n) draw j via threefry2x32
//      (partitionable mode) and atomicMax order k into winner[j] if j < n
//   grid.sync
//   C: gather — out[s] = winner[s] >= 0 ? samples[winner[s]] : buffer[s]
//      16 rows/block in 2 chunks of 8; ALL register-array indices are
//      compile-time constants after unroll (rule #20 — round 2's spill).

#define D_FEAT 1024
#define D4 256                  // float4 per row
#define GRID_BLOCKS 1024
#define BLOCK_THREADS 256

#define ROTL32(x, r) (((x) << (r)) | ((x) >> (32 - (r))))

__device__ __forceinline__ void tf2x32(unsigned k0, unsigned k1,
                                       unsigned x0, unsigned x1,
                                       unsigned& o0, unsigned& o1) {
  const unsigned ks2 = k0 ^ k1 ^ 0x1BD11BDAu;
  x0 += k0; x1 += k1;
  x0 += x1; x1 = ROTL32(x1, 13); x1 ^= x0;
  x0 += x1; x1 = ROTL32(x1, 15); x1 ^= x0;
  x0 += x1; x1 = ROTL32(x1, 26); x1 ^= x0;
  x0 += x1; x1 = ROTL32(x1, 6);  x1 ^= x0;
  x0 += k1; x1 += ks2 + 1u;
  x0 += x1; x1 = ROTL32(x1, 17); x1 ^= x0;
  x0 += x1; x1 = ROTL32(x1, 29); x1 ^= x0;
  x0 += x1; x1 = ROTL32(x1, 16); x1 ^= x0;
  x0 += x1; x1 = ROTL32(x1, 24); x1 ^= x0;
  x0 += ks2; x1 += k0 + 2u;
  x0 += x1; x1 = ROTL32(x1, 13); x1 ^= x0;
  x0 += x1; x1 = ROTL32(x1, 15); x1 ^= x0;
  x0 += x1; x1 = ROTL32(x1, 26); x1 ^= x0;
  x0 += x1; x1 = ROTL32(x1, 6);  x1 ^= x0;
  x0 += k0; x1 += k1 + 3u;
  x0 += x1; x1 = ROTL32(x1, 17); x1 ^= x0;
  x0 += x1; x1 = ROTL32(x1, 29); x1 ^= x0;
  x0 += x1; x1 = ROTL32(x1, 16); x1 ^= x0;
  x0 += x1; x1 = ROTL32(x1, 24); x1 ^= x0;
  x0 += k1; x1 += ks2 + 4u;
  x0 += x1; x1 = ROTL32(x1, 13); x1 ^= x0;
  x0 += x1; x1 = ROTL32(x1, 15); x1 ^= x0;
  x0 += x1; x1 = ROTL32(x1, 26); x1 ^= x0;
  x0 += x1; x1 = ROTL32(x1, 6);  x1 ^= x0;
  x0 += ks2; x1 += k0 + 5u;
  o0 = x0; o1 = x1;
}

__global__ __launch_bounds__(BLOCK_THREADS, 4)
void reservoir_all(const int* __restrict__ i0p,
                   const float4* __restrict__ buf,
                   const float4* __restrict__ smp,
                   int* __restrict__ winner,
                   float4* __restrict__ out,
                   int N, int n) {
  const int tid = blockIdx.x * blockDim.x + threadIdx.x;
  const int nth = gridDim.x * blockDim.x;
  const int i0 = i0p[0];

  // ---- Phase A: fill-phase winners
  for (int s = tid; s < n; s += nth) {
    const int k = s - i0;
    winner[s] = (k >= 0 && k < N) ? k : -1;
  }

  cg::this_grid().sync();

  // ---- Phase B: random-phase samples
  for (int k = tid; k < N; k += nth) {
    const int idx = i0 + k;
    if (idx < n) continue;
    unsigned k1a, k1b, k2a, k2b;
    tf2x32(0u, 42u, 0u, 0u, k1a, k1b);   // const-folded split of key(42)
    tf2x32(0u, 42u, 0u, 1u, k2a, k2b);
    unsigned b1, b2;
    tf2x32(k1a, k1b, 0u, (unsigned)k, b1, b2);
    const unsigned hb = b1 ^ b2;
    tf2x32(k2a, k2b, 0u, (unsigned)k, b1, b2);
    const unsigned lb = b1 ^ b2;
    const unsigned span = (unsigned)(idx + 1);
    unsigned mult = 65536u % span;
    mult = (mult * mult) % span;
    const unsigned j = ((hb % span) * mult + (lb % span)) % span;
    if (j < (unsigned)n) atomicMax(&winner[j], k);
  }

  cg::this_grid().sync();

  // ---- Phase C: gather, 16 rows/block = 2 chunks of 8, static indices only
  const int t = threadIdx.x;
  for (int base = blockIdx.x * 16; base < n; base += gridDim.x * 16) {
    #pragma unroll
    for (int c = 0; c < 2; ++c) {
      const int r0 = base + c * 8;
      if (r0 + 8 <= n) {
        int w[8];
        #pragma unroll
        for (int j = 0; j < 8; ++j) w[j] = winner[r0 + j];
        float4 v[8];
        #pragma unroll
        for (int j = 0; j < 8; ++j) {
          const float4* src = (w[j] >= 0) ? (smp + (size_t)w[j] * D4)
                                          : (buf + (size_t)(r0 + j) * D4);
          v[j] = src[t];
        }
        #pragma unroll
        for (int j = 0; j < 8; ++j)
          out[(size_t)(r0 + j) * D4 + t] = v[j];
      } else {
        for (int r = r0; r < n; ++r) {
          const int wr = winner[r];
          const float4* src = (wr >= 0) ? (smp + (size_t)wr * D4)
                                        : (buf + (size_t)r * D4);
          out[(size_t)r * D4 + t] = src[t];
        }
      }
    }
  }
}

extern "C" void kernel_launch(void* const* d_in, const int* in_sizes, int n_in,
                              void* d_out, int out_size, void* d_ws, size_t ws_size,
                              hipStream_t stream) {
  const float4* buffer  = (const float4*)d_in[0];
  const float4* samples = (const float4*)d_in[1];
  const int*    i0p     = (const int*)d_in[2];
  float4* out = (float4*)d_out;

  int n = out_size / D_FEAT;              // 16384 reservoir slots
  int N = in_sizes[1] / D_FEAT;           // 65536 incoming samples
  int* winner = (int*)d_ws;

  void* args[] = {(void*)&i0p, (void*)&buffer, (void*)&samples,
                  (void*)&winner, (void*)&out, (void*)&N, (void*)&n};
  hipLaunchCooperativeKernel((const void*)reservoir_all,
                             dim3(GRID_BLOCKS), dim3(BLOCK_THREADS),
                             args, 0, stream);
}

// Round 6
// 33.289 us; speedup vs baseline: 5.5753x; 5.5753x over previous
//
#include <hip/hip_runtime.h>

// Reservoir sampling "add" — 3 dispatches (cooperative launch proven 6x slow):
//   K1 init_winner: winner[s] = fill-phase winner (s-i0 if in [0,N)) else -1.
//   K2 random_winner: samples with idx >= n draw j via threefry2x32
//      (partitionable mode, matches modern JAX) and atomicMax order k
//      into winner[j] when j < n.
//   K3 gather8: out[s] = winner[s] >= 0 ? samples[winner[s]] : buffer[s].
//      8 rows per block, fully unrolled, 8 independent 16B loads in flight,
//      NON-TEMPORAL stores via clang ext_vector float4 (HIP float4 is a
//      class type the builtin rejects).

#define D_FEAT 1024
#define D4 256            // float4 per row
#define ROWS_PER_BLOCK 8

typedef float vfloat4 __attribute__((ext_vector_type(4)));

#define ROTL32(x, r) (((x) << (r)) | ((x) >> (32 - (r))))

__device__ __forceinline__ void tf2x32(unsigned k0, unsigned k1,
                                       unsigned x0, unsigned x1,
                                       unsigned& o0, unsigned& o1) {
  const unsigned ks2 = k0 ^ k1 ^ 0x1BD11BDAu;
  x0 += k0; x1 += k1;
  x0 += x1; x1 = ROTL32(x1, 13); x1 ^= x0;
  x0 += x1; x1 = ROTL32(x1, 15); x1 ^= x0;
  x0 += x1; x1 = ROTL32(x1, 26); x1 ^= x0;
  x0 += x1; x1 = ROTL32(x1, 6);  x1 ^= x0;
  x0 += k1; x1 += ks2 + 1u;
  x0 += x1; x1 = ROTL32(x1, 17); x1 ^= x0;
  x0 += x1; x1 = ROTL32(x1, 29); x1 ^= x0;
  x0 += x1; x1 = ROTL32(x1, 16); x1 ^= x0;
  x0 += x1; x1 = ROTL32(x1, 24); x1 ^= x0;
  x0 += ks2; x1 += k0 + 2u;
  x0 += x1; x1 = ROTL32(x1, 13); x1 ^= x0;
  x0 += x1; x1 = ROTL32(x1, 15); x1 ^= x0;
  x0 += x1; x1 = ROTL32(x1, 26); x1 ^= x0;
  x0 += x1; x1 = ROTL32(x1, 6);  x1 ^= x0;
  x0 += k0; x1 += k1 + 3u;
  x0 += x1; x1 = ROTL32(x1, 17); x1 ^= x0;
  x0 += x1; x1 = ROTL32(x1, 29); x1 ^= x0;
  x0 += x1; x1 = ROTL32(x1, 16); x1 ^= x0;
  x0 += x1; x1 = ROTL32(x1, 24); x1 ^= x0;
  x0 += k1; x1 += ks2 + 4u;
  x0 += x1; x1 = ROTL32(x1, 13); x1 ^= x0;
  x0 += x1; x1 = ROTL32(x1, 15); x1 ^= x0;
  x0 += x1; x1 = ROTL32(x1, 26); x1 ^= x0;
  x0 += x1; x1 = ROTL32(x1, 6);  x1 ^= x0;
  x0 += ks2; x1 += k0 + 5u;
  o0 = x0; o1 = x1;
}

__global__ __launch_bounds__(256)
void init_winner(const int* __restrict__ i0p, int* __restrict__ winner,
                 int N, int n) {
  const int s = blockIdx.x * blockDim.x + threadIdx.x;
  if (s >= n) return;
  const int k = s - i0p[0];   // fill-phase sample order targeting slot s
  winner[s] = (k >= 0 && k < N) ? k : -1;
}

__global__ __launch_bounds__(256)
void random_winner(const int* __restrict__ i0p, int* __restrict__ winner,
                   int N, int n) {
  const int k = blockIdx.x * blockDim.x + threadIdx.x;
  if (k >= N) return;
  const int idx = i0p[0] + k;
  if (idx < n) return;                    // fill phase handled by init_winner
  // split subkeys of jax.random.key(42) — constant args, const-folded
  unsigned k1a, k1b, k2a, k2b;
  tf2x32(0u, 42u, 0u, 0u, k1a, k1b);
  tf2x32(0u, 42u, 0u, 1u, k2a, k2b);
  unsigned b1, b2;
  tf2x32(k1a, k1b, 0u, (unsigned)k, b1, b2);
  const unsigned hb = b1 ^ b2;
  tf2x32(k2a, k2b, 0u, (unsigned)k, b1, b2);
  const unsigned lb = b1 ^ b2;
  const unsigned span = (unsigned)(idx + 1);
  unsigned mult = 65536u % span;
  mult = (mult * mult) % span;
  const unsigned j = ((hb % span) * mult + (lb % span)) % span;
  if (j < (unsigned)n) atomicMax(&winner[j], k);
}

__global__ __launch_bounds__(256)
void gather8(const vfloat4* __restrict__ buf, const vfloat4* __restrict__ smp,
             const int* __restrict__ winner, vfloat4* __restrict__ out, int n) {
  const int t = threadIdx.x;                     // float4 column, 0..255
  const int r0 = blockIdx.x * ROWS_PER_BLOCK;

  if (r0 + ROWS_PER_BLOCK <= n) {
    // source pointers (winner is block-uniform, L2-hot)
    const vfloat4* src[ROWS_PER_BLOCK];
    #pragma unroll
    for (int j = 0; j < ROWS_PER_BLOCK; ++j) {
      const int w = winner[r0 + j];
      src[j] = (w >= 0) ? (smp + (size_t)w * D4)
                        : (buf + (size_t)(r0 + j) * D4);
    }
    // 8 independent 16B loads in flight
    vfloat4 v[ROWS_PER_BLOCK];
    #pragma unroll
    for (int j = 0; j < ROWS_PER_BLOCK; ++j) v[j] = src[j][t];
    // non-temporal stores: out is never re-read
    #pragma unroll
    for (int j = 0; j < ROWS_PER_BLOCK; ++j)
      __builtin_nontemporal_store(v[j], &out[(size_t)(r0 + j) * D4 + t]);
  } else {
    for (int r = r0; r < n; ++r) {
      const int w = winner[r];
      const vfloat4* src = (w >= 0) ? (smp + (size_t)w * D4)
                                    : (buf + (size_t)r * D4);
      __builtin_nontemporal_store(src[t], &out[(size_t)r * D4 + t]);
    }
  }
}

extern "C" void kernel_launch(void* const* d_in, const int* in_sizes, int n_in,
                              void* d_out, int out_size, void* d_ws, size_t ws_size,
                              hipStream_t stream) {
  const vfloat4* buffer  = (const vfloat4*)d_in[0];
  const vfloat4* samples = (const vfloat4*)d_in[1];
  const int*     i0p     = (const int*)d_in[2];
  vfloat4* out = (vfloat4*)d_out;

  const int n = out_size / D_FEAT;        // 16384 reservoir slots
  const int N = in_sizes[1] / D_FEAT;     // 65536 incoming samples
  int* winner = (int*)d_ws;

  init_winner<<<(n + 255) / 256, 256, 0, stream>>>(i0p, winner, N, n);
  random_winner<<<(N + 255) / 256, 256, 0, stream>>>(i0p, winner, N, n);

  const int nblk = (n + ROWS_PER_BLOCK - 1) / ROWS_PER_BLOCK;  // 2048
  gather8<<<nblk, 256, 0, stream>>>(buffer, samples, winner, out, n);
}

// Round 7
// 33.254 us; speedup vs baseline: 5.5813x; 1.0011x over previous
//
#include <hip/hip_runtime.h>

// Reservoir sampling "add" — 3 dispatches (structure is forced):
//   - cooperative fusion runs uncached (~550 GB/s, r2/r4) — rejected
//   - init can't be folded into random (plain-store vs atomicMax race;
//     call-1 d_ws garbage makes init-free atomicMax unsound)
//   K1 init_winner4: winner[s] = -1, int4-vectorized (4096 threads).
//   K2 random_winner: samples with idx >= n draw j via threefry2x32
//      (partitionable mode, matches modern JAX) and atomicMax order k
//      into winner[j] when j < n.  Fill-phase winners are handled
//      analytically in the gather (any random winner k >= n-i0 beats
//      any fill winner s-i0 < n-i0, so max-order is preserved).
//   K3 gather16: out[s] = winner[s] >= 0 ? samples[winner[s]]
//                : (fill valid ? samples[s-i0] : buffer[s]).
//      16 rows/block (1024 blocks = 4/CU exact), 2 chunks of 8 with
//      8 independent 16B loads in flight, NT stores, static indices only.

#define D_FEAT 1024
#define D4 256            // float4 per row
#define ROWS_PER_BLOCK 16

typedef float vfloat4 __attribute__((ext_vector_type(4)));

#define ROTL32(x, r) (((x) << (r)) | ((x) >> (32 - (r))))

__device__ __forceinline__ void tf2x32(unsigned k0, unsigned k1,
                                       unsigned x0, unsigned x1,
                                       unsigned& o0, unsigned& o1) {
  const unsigned ks2 = k0 ^ k1 ^ 0x1BD11BDAu;
  x0 += k0; x1 += k1;
  x0 += x1; x1 = ROTL32(x1, 13); x1 ^= x0;
  x0 += x1; x1 = ROTL32(x1, 15); x1 ^= x0;
  x0 += x1; x1 = ROTL32(x1, 26); x1 ^= x0;
  x0 += x1; x1 = ROTL32(x1, 6);  x1 ^= x0;
  x0 += k1; x1 += ks2 + 1u;
  x0 += x1; x1 = ROTL32(x1, 17); x1 ^= x0;
  x0 += x1; x1 = ROTL32(x1, 29); x1 ^= x0;
  x0 += x1; x1 = ROTL32(x1, 16); x1 ^= x0;
  x0 += x1; x1 = ROTL32(x1, 24); x1 ^= x0;
  x0 += ks2; x1 += k0 + 2u;
  x0 += x1; x1 = ROTL32(x1, 13); x1 ^= x0;
  x0 += x1; x1 = ROTL32(x1, 15); x1 ^= x0;
  x0 += x1; x1 = ROTL32(x1, 26); x1 ^= x0;
  x0 += x1; x1 = ROTL32(x1, 6);  x1 ^= x0;
  x0 += k0; x1 += k1 + 3u;
  x0 += x1; x1 = ROTL32(x1, 17); x1 ^= x0;
  x0 += x1; x1 = ROTL32(x1, 29); x1 ^= x0;
  x0 += x1; x1 = ROTL32(x1, 16); x1 ^= x0;
  x0 += x1; x1 = ROTL32(x1, 24); x1 ^= x0;
  x0 += k1; x1 += ks2 + 4u;
  x0 += x1; x1 = ROTL32(x1, 13); x1 ^= x0;
  x0 += x1; x1 = ROTL32(x1, 15); x1 ^= x0;
  x0 += x1; x1 = ROTL32(x1, 26); x1 ^= x0;
  x0 += x1; x1 = ROTL32(x1, 6);  x1 ^= x0;
  x0 += ks2; x1 += k0 + 5u;
  o0 = x0; o1 = x1;
}

typedef int vint4 __attribute__((ext_vector_type(4)));

__global__ __launch_bounds__(256)
void init_winner4(vint4* __restrict__ winner4, int n4) {
  const int s = blockIdx.x * blockDim.x + threadIdx.x;
  if (s < n4) winner4[s] = (vint4){-1, -1, -1, -1};
}

__global__ __launch_bounds__(256)
void random_winner(const int* __restrict__ i0p, int* __restrict__ winner,
                   int N, int n) {
  const int k = blockIdx.x * blockDim.x + threadIdx.x;
  if (k >= N) return;
  const int idx = i0p[0] + k;
  if (idx < n) return;                    // fill phase: handled analytically
  // split subkeys of jax.random.key(42) — constant args, const-folded
  unsigned k1a, k1b, k2a, k2b;
  tf2x32(0u, 42u, 0u, 0u, k1a, k1b);
  tf2x32(0u, 42u, 0u, 1u, k2a, k2b);
  unsigned b1, b2;
  tf2x32(k1a, k1b, 0u, (unsigned)k, b1, b2);
  const unsigned hb = b1 ^ b2;
  tf2x32(k2a, k2b, 0u, (unsigned)k, b1, b2);
  const unsigned lb = b1 ^ b2;
  const unsigned span = (unsigned)(idx + 1);
  unsigned mult = 65536u % span;
  mult = (mult * mult) % span;
  const unsigned j = ((hb % span) * mult + (lb % span)) % span;
  if (j < (unsigned)n) atomicMax(&winner[j], k);
}

__global__ __launch_bounds__(256)
void gather16(const vfloat4* __restrict__ buf, const vfloat4* __restrict__ smp,
              const int* __restrict__ winner, const int* __restrict__ i0p,
              vfloat4* __restrict__ out, int N, int n) {
  const int t = threadIdx.x;                     // float4 column, 0..255
  const int base = blockIdx.x * ROWS_PER_BLOCK;
  const int i0 = i0p[0];

  #pragma unroll
  for (int c = 0; c < ROWS_PER_BLOCK / 8; ++c) {
    const int r0 = base + c * 8;
    if (r0 + 8 <= n) {
      const vfloat4* src[8];
      #pragma unroll
      for (int j = 0; j < 8; ++j) {
        const int r = r0 + j;
        int w = winner[r];                        // random winner, or -1
        const int fk = r - i0;                    // fill-phase sample order
        if (w < 0 && fk >= 0 && fk < N) w = fk;   // analytic fill winner
        src[j] = (w >= 0) ? (smp + (size_t)w * D4)
                          : (buf + (size_t)r * D4);
      }
      vfloat4 v[8];
      #pragma unroll
      for (int j = 0; j < 8; ++j) v[j] = src[j][t];
      #pragma unroll
      for (int j = 0; j < 8; ++j)
        __builtin_nontemporal_store(v[j], &out[(size_t)(r0 + j) * D4 + t]);
    } else {
      for (int r = r0; r < n; ++r) {
        int w = winner[r];
        const int fk = r - i0;
        if (w < 0 && fk >= 0 && fk < N) w = fk;
        const vfloat4* src = (w >= 0) ? (smp + (size_t)w * D4)
                                      : (buf + (size_t)r * D4);
        __builtin_nontemporal_store(src[t], &out[(size_t)r * D4 + t]);
      }
    }
  }
}

extern "C" void kernel_launch(void* const* d_in, const int* in_sizes, int n_in,
                              void* d_out, int out_size, void* d_ws, size_t ws_size,
                              hipStream_t stream) {
  const vfloat4* buffer  = (const vfloat4*)d_in[0];
  const vfloat4* samples = (const vfloat4*)d_in[1];
  const int*     i0p     = (const int*)d_in[2];
  vfloat4* out = (vfloat4*)d_out;

  const int n = out_size / D_FEAT;        // 16384 reservoir slots
  const int N = in_sizes[1] / D_FEAT;     // 65536 incoming samples
  int* winner = (int*)d_ws;

  const int n4 = n / 4;                   // 4096 int4 stores
  init_winner4<<<(n4 + 255) / 256, 256, 0, stream>>>((vint4*)winner, n4);
  random_winner<<<(N + 255) / 256, 256, 0, stream>>>(i0p, winner, N, n);

  const int nblk = (n + ROWS_PER_BLOCK - 1) / ROWS_PER_BLOCK;  // 1024
  gather16<<<nblk, 256, 0, stream>>>(buffer, samples, winner, i0p, out, N, n);
}